// Round 1
// baseline (316.381 us; speedup 1.0000x reference)
//
#include <hip/hip_runtime.h>
#include <cstdint>
#include <cstddef>

// Problem constants
#define Bsz 65536
#define Dsz 256
#define Fsz 512
#define Psz 256

typedef __attribute__((ext_vector_type(8))) short short8;     // bf16x8 MFMA frag (4 VGPR)
typedef __attribute__((ext_vector_type(4))) short short4v;
typedef __attribute__((ext_vector_type(4))) float float4v;

__device__ inline short f2bf(float f) {
    unsigned u = __builtin_bit_cast(unsigned, f);
    u = (u + 0x7FFFu + ((u >> 16) & 1u)) >> 16;   // RNE
    return (short)u;
}

// ---------------- kernel 0: features -> bf16, zero pws_neg ----------------
__global__ void k_prep(const float* __restrict__ features, short* __restrict__ featb,
                       float* __restrict__ pws_neg) {
    int i = blockIdx.x * 256 + threadIdx.x;       // 512 blocks * 256 = F*D
    featb[i] = f2bf(features[i]);
    if (blockIdx.x == 0) pws_neg[threadIdx.x] = 0.f;   // P == 256
}

// ---------------- kernel 1: p-side precompute ----------------
// p_features = prototypes @ features.T  (fp32), then
//   pwb   = bf16(pf * relu(pf))            [P][F]
//   ppm1b = bf16(relu(pf) - 1)             [P][F]
//   pws_neg[p] += -beta * sum_f pw[p][f]
__global__ void k_pside(const float* __restrict__ features,
                        const float* __restrict__ prototypes,
                        const float* __restrict__ beta_p,
                        short* __restrict__ pwb, short* __restrict__ ppm1b,
                        float* __restrict__ pws_neg) {
    __shared__ float prot[Dsz];
    __shared__ float red[256];
    const int t = threadIdx.x;
    const int p = blockIdx.x >> 1;                 // 512 blocks: 2 per prototype
    const int f = ((blockIdx.x & 1) << 8) + t;     // F = 512
    prot[t] = prototypes[(size_t)p * Dsz + t];
    __syncthreads();
    float acc = 0.f;
    const float* fr = features + (size_t)f * Dsz;
    for (int d = 0; d < Dsz; d += 4) {
        float4v v = *(const float4v*)(fr + d);
        acc += v.x * prot[d] + v.y * prot[d + 1] + v.z * prot[d + 2] + v.w * prot[d + 3];
    }
    float pp = fmaxf(acc, 0.f);
    float pw = acc * pp;
    pwb[(size_t)p * Fsz + f]   = f2bf(pw);
    ppm1b[(size_t)p * Fsz + f] = f2bf(pp - 1.0f);
    red[t] = pw;
    __syncthreads();
    for (int s = 128; s > 0; s >>= 1) {
        if (t < s) red[t] += red[t + s];
        __syncthreads();
    }
    if (t == 0) atomicAdd(&pws_neg[p], -(*beta_p) * red[0]);
}

// ---------------- kernel 2: fused main ----------------
// Per block: 64 rows of x. Stage 1: S = x_tile @ featb^T (F in 64-chunks).
// Epilogue builds A1 = theta*xw + beta*xp, A2 = alpha*xw in LDS (bf16).
// Stage 2: O += A1 @ pw^T + A2 @ ppm1^T.  Final: out = O + pws_neg[col].
#define XPITCH 264   // 256 + 8 bf16 pad (row stride 528 B, 16B-aligned)
#define APITCH 72    // 64 + 8 bf16 pad  (row stride 144 B, 16B-aligned)

__global__ __launch_bounds__(256, 2) void k_main(
    const float* __restrict__ x,
    const short* __restrict__ featb,
    const short* __restrict__ pwb,
    const short* __restrict__ ppm1b,
    const float* __restrict__ pws_neg,
    const float* __restrict__ alpha_p,
    const float* __restrict__ beta_p,
    const float* __restrict__ theta_p,
    float* __restrict__ out)
{
    __shared__ alignas(16) short xb[64 * XPITCH];
    __shared__ alignas(16) short a1b[64 * APITCH];
    __shared__ alignas(16) short a2b[64 * APITCH];

    const int t = threadIdx.x;
    const int wave = t >> 6;
    const int lane = t & 63;
    const int l15 = lane & 15;
    const int l4 = lane >> 4;
    const int64_t row0 = (int64_t)blockIdx.x * 64;

    const float alpha = *alpha_p, beta = *beta_p, theta = *theta_p;

    // ---- stage x tile (64 x 256 fp32) -> bf16 LDS ----
    {
        const float* xp = x + row0 * Dsz;
        #pragma unroll
        for (int i = 0; i < 16; ++i) {
            int idx = i * 1024 + t * 4;              // flat fp32 index, coalesced
            float4v v = *(const float4v*)(xp + idx);
            int r = idx >> 8;
            int c = idx & 255;
            short4v s;
            s.x = f2bf(v.x); s.y = f2bf(v.y); s.z = f2bf(v.z); s.w = f2bf(v.w);
            *(short4v*)&xb[r * XPITCH + c] = s;
        }
    }
    __syncthreads();

    float4v oacc[4][4];
    #pragma unroll
    for (int a = 0; a < 4; ++a)
        #pragma unroll
        for (int b = 0; b < 4; ++b)
            oacc[a][b] = (float4v){0.f, 0.f, 0.f, 0.f};

    for (int fc = 0; fc < 8; ++fc) {
        // ---- stage 1: wave w computes S[16w..16w+16][fc*64..+64] ----
        float4v s[4];
        #pragma unroll
        for (int tn = 0; tn < 4; ++tn) s[tn] = (float4v){0.f, 0.f, 0.f, 0.f};

        const short* xrow = &xb[(16 * wave + l15) * XPITCH + l4 * 8];
        #pragma unroll
        for (int kk = 0; kk < 8; ++kk) {
            short8 af = *(const short8*)(xrow + kk * 32);
            #pragma unroll
            for (int tn = 0; tn < 4; ++tn) {
                const short* fptr = &featb[(size_t)(fc * 64 + tn * 16 + l15) * Dsz + kk * 32 + l4 * 8];
                short8 bf = *(const short8*)fptr;
                s[tn] = __builtin_amdgcn_mfma_f32_16x16x32_bf16(af, bf, s[tn], 0, 0, 0);
            }
        }

        // ---- epilogue: relu-weight, build A1/A2 into LDS ----
        // C layout: row = 16*wave + l4*4 + r, col = tn*16 + l15
        #pragma unroll
        for (int tn = 0; tn < 4; ++tn) {
            #pragma unroll
            for (int r = 0; r < 4; ++r) {
                float sv = s[tn][r];
                float xpres = fmaxf(sv, 0.f);
                float xw = sv * xpres;
                int rr = 16 * wave + l4 * 4 + r;
                int cc = tn * 16 + l15;
                a1b[rr * APITCH + cc] = f2bf(theta * xw + beta * xpres);
                a2b[rr * APITCH + cc] = f2bf(alpha * xw);
            }
        }
        __syncthreads();

        // ---- stage 2: wave w computes O[0..64][64w..64w+64], K = this 64-chunk ----
        #pragma unroll
        for (int kk = 0; kk < 2; ++kk) {
            short8 a1f[4], a2f[4];
            #pragma unroll
            for (int tm = 0; tm < 4; ++tm) {
                int off = (tm * 16 + l15) * APITCH + kk * 32 + l4 * 8;
                a1f[tm] = *(const short8*)&a1b[off];
                a2f[tm] = *(const short8*)&a2b[off];
            }
            #pragma unroll
            for (int tn = 0; tn < 4; ++tn) {
                size_t poff = (size_t)(64 * wave + tn * 16 + l15) * Fsz + fc * 64 + kk * 32 + l4 * 8;
                short8 pwf = *(const short8*)&pwb[poff];
                short8 ppf = *(const short8*)&ppm1b[poff];
                #pragma unroll
                for (int tm = 0; tm < 4; ++tm) {
                    oacc[tm][tn] = __builtin_amdgcn_mfma_f32_16x16x32_bf16(a1f[tm], pwf, oacc[tm][tn], 0, 0, 0);
                    oacc[tm][tn] = __builtin_amdgcn_mfma_f32_16x16x32_bf16(a2f[tm], ppf, oacc[tm][tn], 0, 0, 0);
                }
            }
        }
        __syncthreads();
    }

    // ---- final epilogue: add -beta*pws[col], store fp32 ----
    #pragma unroll
    for (int tn = 0; tn < 4; ++tn) {
        int col = 64 * wave + tn * 16 + l15;
        float pn = pws_neg[col];
        #pragma unroll
        for (int tm = 0; tm < 4; ++tm) {
            int64_t grow = row0 + tm * 16 + l4 * 4;
            #pragma unroll
            for (int r = 0; r < 4; ++r) {
                out[(grow + r) * Psz + col] = oacc[tm][tn][r] + pn;
            }
        }
    }
}

// ---------------- launcher ----------------
extern "C" void kernel_launch(void* const* d_in, const int* in_sizes, int n_in,
                              void* d_out, int out_size, void* d_ws, size_t ws_size,
                              hipStream_t stream) {
    const float* x          = (const float*)d_in[0];
    const float* features   = (const float*)d_in[1];
    const float* prototypes = (const float*)d_in[2];
    const float* alpha      = (const float*)d_in[3];
    const float* beta       = (const float*)d_in[4];
    const float* theta      = (const float*)d_in[5];
    float* out = (float*)d_out;

    // ws layout (787456 B total):
    //   featb  [F][D] bf16 : 262144 B @ 0
    //   pwb    [P][F] bf16 : 262144 B @ 262144
    //   ppm1b  [P][F] bf16 : 262144 B @ 524288
    //   pws_neg[P]   fp32  :   1024 B @ 786432
    char* ws = (char*)d_ws;
    short* featb   = (short*)(ws);
    short* pwb     = (short*)(ws + 262144);
    short* ppm1b   = (short*)(ws + 524288);
    float* pws_neg = (float*)(ws + 786432);

    hipLaunchKernelGGL(k_prep,  dim3(512),  dim3(256), 0, stream, features, featb, pws_neg);
    hipLaunchKernelGGL(k_pside, dim3(512),  dim3(256), 0, stream, features, prototypes, beta,
                       pwb, ppm1b, pws_neg);
    hipLaunchKernelGGL(k_main,  dim3(1024), dim3(256), 0, stream, x, featb, pwb, ppm1b,
                       pws_neg, alpha, beta, theta, out);
}

// Round 2
// 238.303 us; speedup vs baseline: 1.3276x; 1.3276x over previous
//
#include <hip/hip_runtime.h>
#include <cstdint>
#include <cstddef>

#define Bsz 65536
#define Dsz 256
#define Fsz 512
#define Psz 256

typedef __attribute__((ext_vector_type(8))) short short8;
typedef __attribute__((ext_vector_type(4))) short short4v;
typedef __attribute__((ext_vector_type(4))) float float4v;

__device__ inline short f2bf(float f) {
    unsigned u = __builtin_bit_cast(unsigned, f);
    u = (u + 0x7FFFu + ((u >> 16) & 1u)) >> 16;   // RNE
    return (short)u;
}
__device__ inline float bf2f(short s) {
    unsigned u = ((unsigned)(unsigned short)s) << 16;
    return __builtin_bit_cast(float, u);
}

__device__ inline void async16(const void* g, void* l) {
    __builtin_amdgcn_global_load_lds((const __attribute__((address_space(1))) void*)g,
                                     (__attribute__((address_space(3))) void*)l, 16, 0, 0);
}

// ---------------- k_prep: features -> bf16, zero pws_neg ----------------
__global__ void k_prep(const float* __restrict__ features, short* __restrict__ featb,
                       float* __restrict__ pws_neg) {
    int i = blockIdx.x * 256 + threadIdx.x;       // 512*256 = F*D
    featb[i] = f2bf(features[i]);
    if (blockIdx.x == 0) pws_neg[threadIdx.x] = 0.f;
}

// ---------------- k_pside: pwcat = [pw | ppm1] per prototype row ----------------
__global__ void k_pside(const float* __restrict__ features,
                        const float* __restrict__ prototypes,
                        const float* __restrict__ beta_p,
                        short* __restrict__ pwcat, float* __restrict__ pws_neg) {
    __shared__ float prot[Dsz];
    __shared__ float red[256];
    const int t = threadIdx.x;
    const int p = blockIdx.x >> 1;
    const int f = ((blockIdx.x & 1) << 8) + t;
    prot[t] = prototypes[(size_t)p * Dsz + t];
    __syncthreads();
    float acc = 0.f;
    const float* fr = features + (size_t)f * Dsz;
    for (int d = 0; d < Dsz; d += 4) {
        float4v v = *(const float4v*)(fr + d);
        acc += v.x * prot[d] + v.y * prot[d + 1] + v.z * prot[d + 2] + v.w * prot[d + 3];
    }
    float pp = fmaxf(acc, 0.f);
    float pw = acc * pp;
    pwcat[(size_t)p * 1024 + f]       = f2bf(pw);
    pwcat[(size_t)p * 1024 + 512 + f] = f2bf(pp - 1.0f);
    red[t] = pw;
    __syncthreads();
    for (int s = 128; s > 0; s >>= 1) {
        if (t < s) red[t] += red[t + s];
        __syncthreads();
    }
    if (t == 0) atomicAdd(&pws_neg[p], -(*beta_p) * red[0]);
}

// ---------------- k1: S = x @ featb^T, epilogue -> A12 = [A1 | A2] bf16 ----------------
// 128x128 tile, K=256 (4 chunks of 64). XOR-swizzled LDS, global_load_lds for featb.
#define SBPITCH 136   // bf16 pitch for bounce buffer (272 B/row, 16B-aligned reads)

__global__ __launch_bounds__(256, 2) void k1(
    const float* __restrict__ x, const short* __restrict__ featb,
    const float* __restrict__ alpha_p, const float* __restrict__ beta_p,
    const float* __restrict__ theta_p,
    short* __restrict__ A12)
{
    __shared__ char lds[35840];                 // max(32768 staging, 128*136*2 bounce)
    short* As = (short*)lds;                    // [128 m][8 units] swizzled
    short* Bs = (short*)(lds + 16384);          // [128 n][8 units] swizzled
    short* Sb = (short*)lds;                    // bounce, pitch SBPITCH

    const int t = threadIdx.x;
    const int w = t >> 6, lane = t & 63, l15 = lane & 15, l4 = lane >> 4;
    const int rowg = blockIdx.x >> 2, nc = blockIdx.x & 3;
    const float alpha = *alpha_p, beta = *beta_p, theta = *theta_p;

    float4v acc[4][4];
    #pragma unroll
    for (int a = 0; a < 4; ++a)
        #pragma unroll
        for (int b = 0; b < 4; ++b) acc[a][b] = (float4v){0.f, 0.f, 0.f, 0.f};

    const size_t xbase = (size_t)rowg * 128 * Dsz;

    for (int kc = 0; kc < 4; ++kc) {
        __syncthreads();
        // stage x chunk (128x64 fp32 -> bf16, swizzled)
        #pragma unroll
        for (int j = 0; j < 8; ++j) {
            int idx = j * 1024 + t * 4;
            int r = idx >> 6, c = idx & 63;
            float4v v = *(const float4v*)(x + xbase + (size_t)r * Dsz + kc * 64 + c);
            int unit = r * 8 + ((c >> 3) ^ (r & 7));
            short4v s; s.x = f2bf(v.x); s.y = f2bf(v.y); s.z = f2bf(v.z); s.w = f2bf(v.w);
            *(short4v*)((char*)As + unit * 16 + (c & 7) * 2) = s;
        }
        // stage featb chunk (128x64 bf16) via global_load_lds, swizzled source
        #pragma unroll
        for (int j = 0; j < 4; ++j) {
            int u0 = j * 256 + w * 64;
            int u = u0 + lane;
            int m = u >> 3, k8 = (u & 7) ^ (m & 7);
            const short* src = featb + (size_t)(nc * 128 + m) * Dsz + kc * 64 + k8 * 8;
            async16(src, Bs + (size_t)u0 * 8);
        }
        __syncthreads();
        #pragma unroll
        for (int kk = 0; kk < 2; ++kk) {
            short8 af[4], bf[4];
            const int k8 = kk * 4 + l4;
            #pragma unroll
            for (int tm = 0; tm < 4; ++tm) {
                int m = (w & 1) * 64 + tm * 16 + l15;
                af[tm] = *(const short8*)&As[(m * 8 + (k8 ^ (m & 7))) * 8];
            }
            #pragma unroll
            for (int tn = 0; tn < 4; ++tn) {
                int n = (w >> 1) * 64 + tn * 16 + l15;
                bf[tn] = *(const short8*)&Bs[(n * 8 + (k8 ^ (n & 7))) * 8];
            }
            #pragma unroll
            for (int tm = 0; tm < 4; ++tm)
                #pragma unroll
                for (int tn = 0; tn < 4; ++tn)
                    acc[tm][tn] = __builtin_amdgcn_mfma_f32_16x16x32_bf16(af[tm], bf[tn], acc[tm][tn], 0, 0, 0);
        }
    }
    __syncthreads();
    // bounce S (fp32 frags) -> Sb bf16
    #pragma unroll
    for (int tm = 0; tm < 4; ++tm)
        #pragma unroll
        for (int tn = 0; tn < 4; ++tn)
            #pragma unroll
            for (int r = 0; r < 4; ++r) {
                int row = (w & 1) * 64 + tm * 16 + l4 * 4 + r;
                int col = (w >> 1) * 64 + tn * 16 + l15;
                Sb[row * SBPITCH + col] = f2bf(acc[tm][tn][r]);
            }
    __syncthreads();
    // read rows coalesced, compute A1/A2, store 16B-packed
    #pragma unroll
    for (int rep = 0; rep < 8; ++rep) {
        int u = rep * 256 + t;               // 2048 units: row = u>>4, i = u&15
        int row = u >> 4, i = u & 15;
        short8 sv = *(const short8*)&Sb[row * SBPITCH + i * 8];
        short8 a1v, a2v;
        #pragma unroll
        for (int e = 0; e < 8; ++e) {
            float s = bf2f(sv[e]);
            float xp = fmaxf(s, 0.f);
            float xw = s * xp;
            a1v[e] = f2bf(theta * xw + beta * xp);
            a2v[e] = f2bf(alpha * xw);
        }
        size_t grow = (size_t)rowg * 128 + row;
        int gcol = nc * 128 + i * 8;
        *(short8*)&A12[grow * 1024 + gcol]       = a1v;
        *(short8*)&A12[grow * 1024 + 512 + gcol] = a2v;
    }
}

// ---------------- k2: out = A12 @ pwcat^T + pws_neg ----------------
// M=rows, N=256, K=1024. 128x128 tile, 16 K-chunks of 64. Both sides global_load_lds.
__global__ __launch_bounds__(256, 2) void k2(
    const short* __restrict__ A12, const short* __restrict__ pwcat,
    const float* __restrict__ pws_neg, float* __restrict__ out)
{
    __shared__ char lds[32768];
    short* As = (short*)lds;
    short* Bs = (short*)(lds + 16384);

    const int t = threadIdx.x;
    const int w = t >> 6, lane = t & 63, l15 = lane & 15, l4 = lane >> 4;
    const int rowg = blockIdx.x >> 1, nc = blockIdx.x & 1;
    const int n0 = nc * 128;

    float4v acc[4][4];
    #pragma unroll
    for (int a = 0; a < 4; ++a)
        #pragma unroll
        for (int b = 0; b < 4; ++b) acc[a][b] = (float4v){0.f, 0.f, 0.f, 0.f};

    for (int kc = 0; kc < 16; ++kc) {
        __syncthreads();
        #pragma unroll
        for (int j = 0; j < 4; ++j) {
            int u0 = j * 256 + w * 64;
            int u = u0 + lane;
            int m = u >> 3, k8 = (u & 7) ^ (m & 7);
            async16(A12 + (size_t)(rowg * 128 + m) * 1024 + kc * 64 + k8 * 8, As + (size_t)u0 * 8);
            async16(pwcat + (size_t)(n0 + m) * 1024 + kc * 64 + k8 * 8,       Bs + (size_t)u0 * 8);
        }
        __syncthreads();
        #pragma unroll
        for (int kk = 0; kk < 2; ++kk) {
            short8 af[4], bf[4];
            const int k8 = kk * 4 + l4;
            #pragma unroll
            for (int tm = 0; tm < 4; ++tm) {
                int m = (w & 1) * 64 + tm * 16 + l15;
                af[tm] = *(const short8*)&As[(m * 8 + (k8 ^ (m & 7))) * 8];
            }
            #pragma unroll
            for (int tn = 0; tn < 4; ++tn) {
                int n = (w >> 1) * 64 + tn * 16 + l15;
                bf[tn] = *(const short8*)&Bs[(n * 8 + (k8 ^ (n & 7))) * 8];
            }
            #pragma unroll
            for (int tm = 0; tm < 4; ++tm)
                #pragma unroll
                for (int tn = 0; tn < 4; ++tn)
                    acc[tm][tn] = __builtin_amdgcn_mfma_f32_16x16x32_bf16(af[tm], bf[tn], acc[tm][tn], 0, 0, 0);
        }
    }

    #pragma unroll
    for (int tn = 0; tn < 4; ++tn) {
        int col = n0 + (w >> 1) * 64 + tn * 16 + l15;
        float pn = pws_neg[col];
        #pragma unroll
        for (int tm = 0; tm < 4; ++tm) {
            size_t row = (size_t)rowg * 128 + (w & 1) * 64 + tm * 16 + l4 * 4;
            #pragma unroll
            for (int r = 0; r < 4; ++r)
                out[(row + r) * Psz + col] = acc[tm][tn][r] + pn;
        }
    }
}

// ---------------- launcher ----------------
extern "C" void kernel_launch(void* const* d_in, const int* in_sizes, int n_in,
                              void* d_out, int out_size, void* d_ws, size_t ws_size,
                              hipStream_t stream) {
    const float* x          = (const float*)d_in[0];
    const float* features   = (const float*)d_in[1];
    const float* prototypes = (const float*)d_in[2];
    const float* alpha      = (const float*)d_in[3];
    const float* beta       = (const float*)d_in[4];
    const float* theta      = (const float*)d_in[5];
    float* out = (float*)d_out;

    // ws layout: featb @0 (256KB), pwcat @262144 (512KB), pws_neg @786432 (1KB),
    //            A12 strip @790528 (rows*2048 B)
    char* ws = (char*)d_ws;
    short* featb   = (short*)(ws);
    short* pwcat   = (short*)(ws + 262144);
    float* pws_neg = (float*)(ws + 786432);
    short* A12     = (short*)(ws + 790528);

    // adaptive striping over available workspace (ws_size constant per session)
    long fit = ((long)ws_size - 790528) / 2048;
    if (fit > Bsz) fit = Bsz;
    long rowsPer = (fit / 128) * 128;
    if (rowsPer < 128) rowsPer = 128;   // assume ws is at least ~1.1 MB

    hipLaunchKernelGGL(k_prep,  dim3(512), dim3(256), 0, stream, features, featb, pws_neg);
    hipLaunchKernelGGL(k_pside, dim3(512), dim3(256), 0, stream, features, prototypes, beta,
                       pwcat, pws_neg);

    for (long start = 0; start < Bsz; start += rowsPer) {
        long rows = Bsz - start; if (rows > rowsPer) rows = rowsPer;
        const float* x_s = x + start * Dsz;
        float* out_s = out + start * Psz;
        hipLaunchKernelGGL(k1, dim3((unsigned)((rows >> 7) * 4)), dim3(256), 0, stream,
                           x_s, featb, alpha, beta, theta, A12);
        hipLaunchKernelGGL(k2, dim3((unsigned)((rows >> 7) * 2)), dim3(256), 0, stream,
                           A12, pwcat, pws_neg, out_s);
    }
}

// Round 3
// 226.204 us; speedup vs baseline: 1.3987x; 1.0535x over previous
//
#include <hip/hip_runtime.h>
#include <cstdint>
#include <cstddef>

#define Bsz 65536
#define Dsz 256
#define Fsz 512
#define Psz 256

typedef __attribute__((ext_vector_type(8))) short short8;
typedef __attribute__((ext_vector_type(4))) float float4v;

__device__ inline short f2bf(float f) {
    unsigned u = __builtin_bit_cast(unsigned, f);
    u = (u + 0x7FFFu + ((u >> 16) & 1u)) >> 16;   // RNE
    return (short)u;
}

__device__ inline void async16(const void* g, void* l) {
    __builtin_amdgcn_global_load_lds((const __attribute__((address_space(1))) void*)g,
                                     (__attribute__((address_space(3))) void*)l, 16, 0, 0);
}

// ---------------- k_prep: features -> bf16, zero pws_neg ----------------
__global__ void k_prep(const float* __restrict__ features, short* __restrict__ featb,
                       float* __restrict__ pws_neg) {
    int i = blockIdx.x * 256 + threadIdx.x;       // 512*256 = F*D
    featb[i] = f2bf(features[i]);
    if (blockIdx.x == 0) pws_neg[threadIdx.x] = 0.f;
}

// ---------------- k_pside: pw / ppm1 / pws_neg ----------------
__global__ void k_pside(const float* __restrict__ features,
                        const float* __restrict__ prototypes,
                        const float* __restrict__ beta_p,
                        short* __restrict__ pwt, short* __restrict__ ppm1t,
                        float* __restrict__ pws_neg) {
    __shared__ float prot[Dsz];
    __shared__ float red[256];
    const int t = threadIdx.x;
    const int p = blockIdx.x >> 1;
    const int f = ((blockIdx.x & 1) << 8) + t;
    prot[t] = prototypes[(size_t)p * Dsz + t];
    __syncthreads();
    float acc = 0.f;
    const float* fr = features + (size_t)f * Dsz;
    for (int d = 0; d < Dsz; d += 4) {
        float4v v = *(const float4v*)(fr + d);
        acc += v.x * prot[d] + v.y * prot[d + 1] + v.z * prot[d + 2] + v.w * prot[d + 3];
    }
    float pp = fmaxf(acc, 0.f);
    float pw = acc * pp;
    pwt[(size_t)p * Fsz + f]   = f2bf(pw);
    ppm1t[(size_t)p * Fsz + f] = f2bf(pp - 1.0f);
    red[t] = pw;
    __syncthreads();
    for (int s = 128; s > 0; s >>= 1) {
        if (t < s) red[t] += red[t + s];
        __syncthreads();
    }
    if (t == 0) atomicAdd(&pws_neg[p], -(*beta_p) * red[0]);
}

// ---------------- k_main: fully fused ----------------
// Block: 128 x-rows, all 256 P. F in 16 chunks of 32.
// Stage 1: S = x(128x256) @ featb_chunk(32x256)^T, x A-frags live in VGPRs.
// Epilogue: A1 = theta*xw + beta*xp, A2 = alpha*xw -> LDS (16 KB).
// Stage 2: acc += A1 @ pw_chunk^T + A2 @ ppm1_chunk^T (128x256 in regs).
__global__ __launch_bounds__(256, 2) void k_main(
    const float* __restrict__ x, const short* __restrict__ featb,
    const short* __restrict__ pwt, const short* __restrict__ ppm1t,
    const float* __restrict__ pws_neg,
    const float* __restrict__ alpha_p, const float* __restrict__ beta_p,
    const float* __restrict__ theta_p, float* __restrict__ out)
{
    __shared__ char lds[65536];
    short* A1 = (short*)(lds);            // [128][32] pair-XOR8, 8 KB
    short* A2 = (short*)(lds + 8192);     // 8 KB
    short* FB = (short*)(lds + 16384);    // [32][256] row-XOR8, 16 KB
    short* PW = (short*)(lds + 32768);    // [256][32] pair-XOR8, 16 KB
    short* PM = (short*)(lds + 49152);    // 16 KB
    short* XB = (short*)(lds + 16384);    // x bounce [64][256], 32 KB (aliases FB+PW)

    const int t = threadIdx.x;
    const int w = t >> 6, lane = t & 63, l15 = lane & 15, l4 = lane >> 4;
    const float alpha = *alpha_p, beta = *beta_p, theta = *theta_p;
    const size_t row0 = (size_t)blockIdx.x * 128;

    // ---- load x tile once: bounce 64 rows at a time, extract A-frags to regs ----
    short8 xreg[2][8];
    for (int p = 0; p < 2; ++p) {
        const float* xp = x + (row0 + p * 64) * Dsz;
        #pragma unroll
        for (int j = 0; j < 8; ++j) {
            int idx = j * 2048 + t * 8;
            int r = idx >> 8, c = idx & 255;
            float4v v0 = *(const float4v*)(xp + r * Dsz + c);
            float4v v1 = *(const float4v*)(xp + r * Dsz + c + 4);
            short8 s;
            s[0] = f2bf(v0.x); s[1] = f2bf(v0.y); s[2] = f2bf(v0.z); s[3] = f2bf(v0.w);
            s[4] = f2bf(v1.x); s[5] = f2bf(v1.y); s[6] = f2bf(v1.z); s[7] = f2bf(v1.w);
            *(short8*)&XB[(r * 32 + ((c >> 3) ^ (r & 7))) * 8] = s;
        }
        __syncthreads();
        if ((w >> 1) == p) {                      // waves 0,1 own rows 0..63; 2,3 own 64..127
            int m0 = (w & 1) * 32;
            #pragma unroll
            for (int tm = 0; tm < 2; ++tm) {
                int m = m0 + tm * 16 + l15;
                #pragma unroll
                for (int kk = 0; kk < 8; ++kk)
                    xreg[tm][kk] = *(const short8*)&XB[(m * 32 + ((kk * 4 + l4) ^ (m & 7))) * 8];
            }
        }
        __syncthreads();
    }

    float4v acc[4][8];
    #pragma unroll
    for (int a = 0; a < 4; ++a)
        #pragma unroll
        for (int b = 0; b < 8; ++b) acc[a][b] = (float4v){0.f, 0.f, 0.f, 0.f};

    const int rr0 = 64 * (w & 1), cc0 = 128 * (w >> 1);

    for (int kc = 0; kc < 16; ++kc) {
        __syncthreads();                           // prev stage-2 reads done
        // ---- stage B-side chunks via global_load_lds ----
        #pragma unroll
        for (int j = 0; j < 4; ++j) {
            int u0 = j * 256 + w * 64;
            int u = u0 + lane;
            {   // featb chunk: [32 f][256 d], u = f*32 + (g ^ (f&7))
                int r = u >> 5, g = (u & 31) ^ (r & 7);
                async16(featb + (((size_t)(kc * 32 + r)) << 8) + g * 8, FB + (size_t)u0 * 8);
            }
            {   // pw/ppm1 chunk: [256 p][32 f], u = (p>>1)*8 + ((((p&1)<<2)|g) ^ ((p>>1)&7))
                int rp = u >> 3, h = (u & 7) ^ (rp & 7), r = rp * 2 + (h >> 2), g = h & 3;
                async16(pwt   + (size_t)r * Fsz + kc * 32 + g * 8, PW + (size_t)u0 * 8);
                async16(ppm1t + (size_t)r * Fsz + kc * 32 + g * 8, PM + (size_t)u0 * 8);
            }
        }
        __syncthreads();                           // staging complete

        // ---- stage 1: S rows 32w..32w+32, cols = this F-chunk (32) ----
        float4v sacc[2][2];
        #pragma unroll
        for (int a = 0; a < 2; ++a)
            #pragma unroll
            for (int b = 0; b < 2; ++b) sacc[a][b] = (float4v){0.f, 0.f, 0.f, 0.f};
        #pragma unroll
        for (int kk = 0; kk < 8; ++kk) {
            int s0 = (kk * 4 + l4) ^ (l15 & 7);
            short8 b0 = *(const short8*)&FB[(l15 * 32 + s0) * 8];
            short8 b1 = *(const short8*)&FB[((l15 + 16) * 32 + s0) * 8];
            sacc[0][0] = __builtin_amdgcn_mfma_f32_16x16x32_bf16(xreg[0][kk], b0, sacc[0][0], 0, 0, 0);
            sacc[0][1] = __builtin_amdgcn_mfma_f32_16x16x32_bf16(xreg[0][kk], b1, sacc[0][1], 0, 0, 0);
            sacc[1][0] = __builtin_amdgcn_mfma_f32_16x16x32_bf16(xreg[1][kk], b0, sacc[1][0], 0, 0, 0);
            sacc[1][1] = __builtin_amdgcn_mfma_f32_16x16x32_bf16(xreg[1][kk], b1, sacc[1][1], 0, 0, 0);
        }
        // ---- epilogue: Tversky weights -> A1/A2 LDS ----
        #pragma unroll
        for (int tm = 0; tm < 2; ++tm)
            #pragma unroll
            for (int tn = 0; tn < 2; ++tn)
                #pragma unroll
                for (int r = 0; r < 4; ++r) {
                    float sv = sacc[tm][tn][r];
                    float xp2 = fmaxf(sv, 0.f);
                    float xw = sv * xp2;
                    int row = 32 * w + tm * 16 + l4 * 4 + r;
                    int kcol = tn * 16 + l15;
                    int g = kcol >> 3, bb = kcol & 7;
                    int rp = row >> 1;
                    int u = rp * 8 + (((((row & 1) << 2) | g)) ^ (rp & 7));
                    A1[u * 8 + bb] = f2bf(theta * xw + beta * xp2);
                    A2[u * 8 + bb] = f2bf(alpha * xw);
                }
        __syncthreads();                           // A1/A2 visible

        // ---- stage 2: acc += A1 @ pw^T + A2 @ ppm1^T ----
        #pragma unroll
        for (int half = 0; half < 2; ++half) {
            short8 bw[4], bm[4];
            #pragma unroll
            for (int tn = 0; tn < 4; ++tn) {
                int n = cc0 + (half * 4 + tn) * 16 + l15;
                int rp = n >> 1;
                int u = rp * 8 + ((((n & 1) << 2) | l4) ^ (rp & 7));
                bw[tn] = *(const short8*)&PW[u * 8];
                bm[tn] = *(const short8*)&PM[u * 8];
            }
            #pragma unroll
            for (int tm = 0; tm < 4; ++tm) {
                int m = rr0 + tm * 16 + l15;
                int rp = m >> 1;
                int u = rp * 8 + ((((m & 1) << 2) | l4) ^ (rp & 7));
                short8 a1f = *(const short8*)&A1[u * 8];
                short8 a2f = *(const short8*)&A2[u * 8];
                #pragma unroll
                for (int tn = 0; tn < 4; ++tn) {
                    acc[tm][half * 4 + tn] = __builtin_amdgcn_mfma_f32_16x16x32_bf16(a1f, bw[tn], acc[tm][half * 4 + tn], 0, 0, 0);
                    acc[tm][half * 4 + tn] = __builtin_amdgcn_mfma_f32_16x16x32_bf16(a2f, bm[tn], acc[tm][half * 4 + tn], 0, 0, 0);
                }
            }
        }
    }

    // ---- final epilogue: add pws_neg, store ----
    #pragma unroll
    for (int tn = 0; tn < 8; ++tn) {
        int col = cc0 + tn * 16 + l15;
        float pn = pws_neg[col];
        #pragma unroll
        for (int tm = 0; tm < 4; ++tm) {
            size_t grow = row0 + rr0 + tm * 16 + l4 * 4;
            #pragma unroll
            for (int r = 0; r < 4; ++r)
                out[(grow + r) * Psz + col] = acc[tm][tn][r] + pn;
        }
    }
}

// ---------------- launcher ----------------
extern "C" void kernel_launch(void* const* d_in, const int* in_sizes, int n_in,
                              void* d_out, int out_size, void* d_ws, size_t ws_size,
                              hipStream_t stream) {
    const float* x          = (const float*)d_in[0];
    const float* features   = (const float*)d_in[1];
    const float* prototypes = (const float*)d_in[2];
    const float* alpha      = (const float*)d_in[3];
    const float* beta       = (const float*)d_in[4];
    const float* theta      = (const float*)d_in[5];
    float* out = (float*)d_out;

    // ws: featb 256KB @0, pwt 256KB @262144, ppm1t 256KB @524288, pws_neg 1KB @786432
    char* ws = (char*)d_ws;
    short* featb   = (short*)(ws);
    short* pwt     = (short*)(ws + 262144);
    short* ppm1t   = (short*)(ws + 524288);
    float* pws_neg = (float*)(ws + 786432);

    hipLaunchKernelGGL(k_prep,  dim3(512), dim3(256), 0, stream, features, featb, pws_neg);
    hipLaunchKernelGGL(k_pside, dim3(512), dim3(256), 0, stream, features, prototypes, beta,
                       pwt, ppm1t, pws_neg);
    hipLaunchKernelGGL(k_main,  dim3(512), dim3(256), 0, stream, x, featb, pwt, ppm1t,
                       pws_neg, alpha, beta, theta, out);
}

// Round 5
// 215.194 us; speedup vs baseline: 1.4702x; 1.0512x over previous
//
#include <hip/hip_runtime.h>
#include <cstdint>
#include <cstddef>

#define Bsz 65536
#define Dsz 256
#define Fsz 512
#define Psz 256

typedef __attribute__((ext_vector_type(8))) short short8;
typedef __attribute__((ext_vector_type(4))) short short4v;
typedef __attribute__((ext_vector_type(4))) float float4v;
typedef __attribute__((ext_vector_type(16))) float float16v;

__device__ inline short f2bf(float f) {
    unsigned u = __builtin_bit_cast(unsigned, f);
    u = (u + 0x7FFFu + ((u >> 16) & 1u)) >> 16;   // RNE
    return (short)u;
}
__device__ inline float bf2f(short s) {
    unsigned u = ((unsigned)(unsigned short)s) << 16;
    return __builtin_bit_cast(float, u);
}
__device__ inline void async16(const void* g, void* l) {
    __builtin_amdgcn_global_load_lds((const __attribute__((address_space(1))) void*)g,
                                     (__attribute__((address_space(3))) void*)l, 16, 0, 0);
}

// ---------------- k_prep: features -> bf16, zero pws_neg ----------------
__global__ void k_prep(const float* __restrict__ features, short* __restrict__ featb,
                       float* __restrict__ pws_neg) {
    int i = blockIdx.x * 256 + threadIdx.x;       // 512*256 = F*D
    featb[i] = f2bf(features[i]);
    if (blockIdx.x == 0) pws_neg[threadIdx.x] = 0.f;
}

// ---------------- k_pside: MFMA GEMM pf = prototypes @ featb^T ----------------
// 8 blocks: rowg = blk>>2 (128 p-rows), nc = blk&3 (128 f-cols). K=256.
#define SBPITCH 136

__global__ __launch_bounds__(256, 2) void k_pside(
    const float* __restrict__ prototypes, const short* __restrict__ featb,
    const float* __restrict__ beta_p,
    short* __restrict__ pwt, short* __restrict__ ppm1t, float* __restrict__ pws_neg)
{
    __shared__ char lds[35840];
    short* As = (short*)lds;
    short* Bs = (short*)(lds + 16384);
    short* Sb = (short*)lds;

    const int t = threadIdx.x;
    const int w = t >> 6, lane = t & 63, l15 = lane & 15, l4 = lane >> 4;
    const int rowg = blockIdx.x >> 2, nc = blockIdx.x & 3;
    const float beta = *beta_p;

    float4v acc[4][4];
    #pragma unroll
    for (int a = 0; a < 4; ++a)
        #pragma unroll
        for (int b = 0; b < 4; ++b) acc[a][b] = (float4v){0.f, 0.f, 0.f, 0.f};

    const float* pbase = prototypes + (size_t)rowg * 128 * Dsz;

    for (int kc = 0; kc < 4; ++kc) {
        __syncthreads();
        #pragma unroll
        for (int j = 0; j < 8; ++j) {
            int idx = j * 1024 + t * 4;
            int r = idx >> 6, c = idx & 63;
            float4v v = *(const float4v*)(pbase + (size_t)r * Dsz + kc * 64 + c);
            int unit = r * 8 + ((c >> 3) ^ (r & 7));
            short4v s; s.x = f2bf(v.x); s.y = f2bf(v.y); s.z = f2bf(v.z); s.w = f2bf(v.w);
            *(short4v*)((char*)As + unit * 16 + (c & 7) * 2) = s;
        }
        #pragma unroll
        for (int j = 0; j < 4; ++j) {
            int u0 = j * 256 + w * 64;
            int u = u0 + lane;
            int m = u >> 3, k8 = (u & 7) ^ (m & 7);
            async16(featb + (size_t)(nc * 128 + m) * Dsz + kc * 64 + k8 * 8, Bs + (size_t)u0 * 8);
        }
        __syncthreads();
        #pragma unroll
        for (int kk = 0; kk < 2; ++kk) {
            short8 af[4], bf[4];
            const int k8 = kk * 4 + l4;
            #pragma unroll
            for (int tm = 0; tm < 4; ++tm) {
                int m = (w & 1) * 64 + tm * 16 + l15;
                af[tm] = *(const short8*)&As[(m * 8 + (k8 ^ (m & 7))) * 8];
            }
            #pragma unroll
            for (int tn = 0; tn < 4; ++tn) {
                int n = (w >> 1) * 64 + tn * 16 + l15;
                bf[tn] = *(const short8*)&Bs[(n * 8 + (k8 ^ (n & 7))) * 8];
            }
            #pragma unroll
            for (int tm = 0; tm < 4; ++tm)
                #pragma unroll
                for (int tn = 0; tn < 4; ++tn)
                    acc[tm][tn] = __builtin_amdgcn_mfma_f32_16x16x32_bf16(af[tm], bf[tn], acc[tm][tn], 0, 0, 0);
        }
    }
    __syncthreads();
    #pragma unroll
    for (int tm = 0; tm < 4; ++tm)
        #pragma unroll
        for (int tn = 0; tn < 4; ++tn)
            #pragma unroll
            for (int r = 0; r < 4; ++r) {
                int row = (w & 1) * 64 + tm * 16 + l4 * 4 + r;
                int col = (w >> 1) * 64 + tn * 16 + l15;
                Sb[row * SBPITCH + col] = f2bf(acc[tm][tn][r]);
            }
    __syncthreads();
    #pragma unroll
    for (int rep = 0; rep < 8; ++rep) {
        int u = rep * 256 + t;
        int row = u >> 4, i = u & 15;
        short8 sv = *(const short8*)&Sb[row * SBPITCH + i * 8];
        short8 pwv, pmv;
        float sum = 0.f;
        #pragma unroll
        for (int e = 0; e < 8; ++e) {
            float pf = bf2f(sv[e]);
            float pp = fmaxf(pf, 0.f);
            float pw = pf * pp;
            pwv[e] = f2bf(pw);
            pmv[e] = f2bf(pp - 1.0f);
            sum += pw;
        }
        size_t p = (size_t)rowg * 128 + row;
        int gcol = nc * 128 + i * 8;
        *(short8*)&pwt[p * Fsz + gcol]   = pwv;
        *(short8*)&ppm1t[p * Fsz + gcol] = pmv;
        #pragma unroll
        for (int mk = 1; mk < 16; mk <<= 1) sum += __shfl_xor(sum, mk, 64);
        if ((lane & 15) == 0) atomicAdd(&pws_neg[p], -beta * sum);
    }
}

// ---------------- k_main: fused, 64 rows x 256 P per block ----------------
// F in 32 chunks of 16. Stage 1: 16x16x32, x A-frags in regs, S -> A12=[A1|A2] LDS.
// Stage 2: 32x32x16, col-split waves, double-buffered FB/PB staging, 2 barriers/chunk.
// LDS map: FB buf0 @0 (8KB), FB buf1 @8192, PB buf0 @16384 (16KB), PB buf1 @32768,
//          A12 @49152 (4KB). Total 53248.
__global__ __launch_bounds__(256, 3) void k_main(
    const float* __restrict__ x, const short* __restrict__ featb,
    const short* __restrict__ pwt, const short* __restrict__ ppm1t,
    const float* __restrict__ pws_neg,
    const float* __restrict__ alpha_p, const float* __restrict__ beta_p,
    const float* __restrict__ theta_p, float* __restrict__ out)
{
    __shared__ char lds[53248];
    short* const A12 = (short*)(lds + 49152);

    const int t = threadIdx.x;
    const int w = t >> 6, lane = t & 63, l15 = lane & 15, l4 = lane >> 4;
    const int l31 = lane & 31, half = lane >> 5;
    const float alpha = *alpha_p, beta = *beta_p, theta = *theta_p;
    const size_t row0 = (size_t)blockIdx.x * 64;

    // ---- x A-frags: 16 rows per wave, direct global -> regs ----
    short8 xreg[8];
    {
        const float* xr = x + (row0 + 16 * w + l15) * Dsz + l4 * 8;
        #pragma unroll
        for (int kk = 0; kk < 8; ++kk) {
            float4v v0 = *(const float4v*)(xr + kk * 32);
            float4v v1 = *(const float4v*)(xr + kk * 32 + 4);
            short8 s;
            s[0] = f2bf(v0.x); s[1] = f2bf(v0.y); s[2] = f2bf(v0.z); s[3] = f2bf(v0.w);
            s[4] = f2bf(v1.x); s[5] = f2bf(v1.y); s[6] = f2bf(v1.z); s[7] = f2bf(v1.w);
            xreg[kk] = s;
        }
    }

    // staging: FB 512 units (2/thread), PB 1024 units (4/thread)
    auto stage = [&](int kc) {
        int buf = kc & 1;
        short* FB = (short*)(lds + buf * 8192);
        short* PB = (short*)(lds + 16384 + buf * 16384);
        #pragma unroll
        for (int j = 0; j < 2; ++j) {
            int u0 = j * 256 + w * 64;
            int u = u0 + lane;
            int f = u >> 5, gg = (u & 31) ^ (f & 7);
            async16(featb + (size_t)(kc * 16 + f) * Dsz + gg * 8, FB + (size_t)u0 * 8);
        }
        #pragma unroll
        for (int j = 0; j < 4; ++j) {
            int u0 = j * 256 + w * 64;
            int u = u0 + lane;
            int p = u >> 2, sg = u & 3, g = sg ^ ((p >> 1) & 3);
            const short* src = (g < 2)
                ? pwt   + (size_t)p * Fsz + kc * 16 + g * 8
                : ppm1t + (size_t)p * Fsz + kc * 16 + (g - 2) * 8;
            async16(src, PB + (size_t)u0 * 8);
        }
    };

    float16v acc[2][2];
    #pragma unroll
    for (int a = 0; a < 2; ++a)
        #pragma unroll
        for (int b = 0; b < 2; ++b)
            #pragma unroll
            for (int e = 0; e < 16; ++e) acc[a][b][e] = 0.f;

    stage(0);

    for (int kc = 0; kc < 32; ++kc) {
        int buf = kc & 1;
        short* FBc = (short*)(lds + buf * 8192);
        short* PBc = (short*)(lds + 16384 + buf * 16384);
        __syncthreads();                    // staging kc ready; A12 reads of kc-1 done

        // ---- stage 1: S[16 rows][16 f] per wave ----
        float4v s = (float4v){0.f, 0.f, 0.f, 0.f};
        #pragma unroll
        for (int kk = 0; kk < 8; ++kk) {
            int g = kk * 4 + l4;
            short8 bf = *(const short8*)&FBc[(l15 * 32 + (g ^ (l15 & 7))) * 8];
            s = __builtin_amdgcn_mfma_f32_16x16x32_bf16(xreg[kk], bf, s, 0, 0, 0);
        }
        // epilogue -> A12 (A1 at k=l15, A2 at k=16+l15)
        #pragma unroll
        for (int r = 0; r < 4; ++r) {
            float sv = s[r];
            float xp = fmaxf(sv, 0.f);
            float xw = sv * xp;
            int m = 16 * w + l4 * 4 + r;
            int swz = (m >> 1) & 3;
            int u1 = m * 4 + ((l15 >> 3) ^ swz);
            int u2 = m * 4 + ((2 + (l15 >> 3)) ^ swz);
            A12[u1 * 8 + (l15 & 7)] = f2bf(theta * xw + beta * xp);
            A12[u2 * 8 + (l15 & 7)] = f2bf(alpha * xw);
        }
        __syncthreads();                    // A12 ready

        if (kc + 1 < 32) stage(kc + 1);

        // ---- stage 2: 32x32x16, wave cols 64w..64w+64, K=32 (A1|A2) ----
        short8 afr[2][2], bfr[2][2];
        #pragma unroll
        for (int mi = 0; mi < 2; ++mi)
            #pragma unroll
            for (int ks = 0; ks < 2; ++ks) {
                int m = 32 * mi + l31;
                int g = 2 * ks + half;
                afr[mi][ks] = *(const short8*)&A12[(m * 4 + (g ^ ((m >> 1) & 3))) * 8];
            }
        #pragma unroll
        for (int ni = 0; ni < 2; ++ni)
            #pragma unroll
            for (int ks = 0; ks < 2; ++ks) {
                int p = 64 * w + 32 * ni + l31;
                int g = 2 * ks + half;
                bfr[ni][ks] = *(const short8*)&PBc[(p * 4 + (g ^ ((p >> 1) & 3))) * 8];
            }
        #pragma unroll
        for (int mi = 0; mi < 2; ++mi)
            #pragma unroll
            for (int ni = 0; ni < 2; ++ni) {
                acc[mi][ni] = __builtin_amdgcn_mfma_f32_32x32x16_bf16(afr[mi][0], bfr[ni][0], acc[mi][ni], 0, 0, 0);
                acc[mi][ni] = __builtin_amdgcn_mfma_f32_32x32x16_bf16(afr[mi][1], bfr[ni][1], acc[mi][ni], 0, 0, 0);
            }
    }

    // ---- output: C layout col=lane&31, row=(reg&3)+8*(reg>>2)+4*half ----
    #pragma unroll
    for (int ni = 0; ni < 2; ++ni) {
        int col = 64 * w + 32 * ni + l31;
        float pn = pws_neg[col];
        #pragma unroll
        for (int mi = 0; mi < 2; ++mi)
            #pragma unroll
            for (int rg = 0; rg < 16; ++rg) {
                size_t grow = row0 + 32 * mi + (rg & 3) + 8 * (rg >> 2) + 4 * half;
                out[grow * Psz + col] = acc[mi][ni][rg] + pn;
            }
    }
}

// ---------------- launcher ----------------
extern "C" void kernel_launch(void* const* d_in, const int* in_sizes, int n_in,
                              void* d_out, int out_size, void* d_ws, size_t ws_size,
                              hipStream_t stream) {
    const float* x          = (const float*)d_in[0];
    const float* features   = (const float*)d_in[1];
    const float* prototypes = (const float*)d_in[2];
    const float* alpha      = (const float*)d_in[3];
    const float* beta       = (const float*)d_in[4];
    const float* theta      = (const float*)d_in[5];
    float* out = (float*)d_out;

    // ws: featb 256KB @0, pwt 256KB @262144, ppm1t 256KB @524288, pws_neg 1KB @786432
    char* ws = (char*)d_ws;
    short* featb   = (short*)(ws);
    short* pwt     = (short*)(ws + 262144);
    short* ppm1t   = (short*)(ws + 524288);
    float* pws_neg = (float*)(ws + 786432);

    hipLaunchKernelGGL(k_prep,  dim3(512),  dim3(256), 0, stream, features, featb, pws_neg);
    hipLaunchKernelGGL(k_pside, dim3(8),    dim3(256), 0, stream, prototypes, featb, beta,
                       pwt, ppm1t, pws_neg);
    hipLaunchKernelGGL(k_main,  dim3(1024), dim3(256), 0, stream, x, featb, pwt, ppm1t,
                       pws_neg, alpha, beta, theta, out);
}

// Round 6
// 194.807 us; speedup vs baseline: 1.6241x; 1.1047x over previous
//
#include <hip/hip_runtime.h>
#include <cstdint>
#include <cstddef>

#define Bsz 65536
#define Dsz 256
#define Fsz 512
#define Psz 256

typedef __attribute__((ext_vector_type(8))) short short8;
typedef __attribute__((ext_vector_type(4))) short short4v;
typedef __attribute__((ext_vector_type(4))) float float4v;
typedef __attribute__((ext_vector_type(16))) float float16v;

__device__ inline short f2bf(float f) {
    unsigned u = __builtin_bit_cast(unsigned, f);
    u = (u + 0x7FFFu + ((u >> 16) & 1u)) >> 16;   // RNE
    return (short)u;
}
__device__ inline float bf2f(short s) {
    unsigned u = ((unsigned)(unsigned short)s) << 16;
    return __builtin_bit_cast(float, u);
}

// Fragment-ordered layouts (all addresses in shorts):
//   featbB[fc 0..31][kk 0..7][lane 0..63][j 0..7]   : element featb[f][d],
//       fc=f>>4, kk=d>>5, lane=(f&15)+16*((d>>3)&3), j=d&7
//   pwB/pmB[fc 0..31][cg 0..3][ni 0..1][lane 0..63][j 0..7] : element pw[p][f],
//       fc=f>>4, cg=p>>6, ni=(p>>5)&1, lane=(p&31)+32*((f>>3)&1), j=f&7

// ---------------- k_prep: features -> featbB (fragment order), zero pws_neg ----------------
__global__ void k_prep(const float* __restrict__ features, short* __restrict__ featbB,
                       float* __restrict__ pws_neg) {
    int idx = blockIdx.x * 256 + threadIdx.x;      // 64 blocks * 256 = 16384 = F*D/8
    int f = idx >> 5, d0 = (idx & 31) * 8;
    float4v v0 = *(const float4v*)(features + (size_t)f * Dsz + d0);
    float4v v1 = *(const float4v*)(features + (size_t)f * Dsz + d0 + 4);
    short8 s;
    s[0] = f2bf(v0.x); s[1] = f2bf(v0.y); s[2] = f2bf(v0.z); s[3] = f2bf(v0.w);
    s[4] = f2bf(v1.x); s[5] = f2bf(v1.y); s[6] = f2bf(v1.z); s[7] = f2bf(v1.w);
    int lane = (f & 15) + 16 * ((d0 >> 3) & 3);
    size_t o = (size_t)(f >> 4) * 4096 + (size_t)(d0 >> 5) * 512 + (size_t)lane * 8;
    *(short8*)&featbB[o] = s;
    if (idx < Psz) pws_neg[idx] = 0.f;
}

// ---------------- k_pside: pf = prototypes @ featb^T; emit pwB/pmB fragged + pws_neg ----------------
#define SBPITCH 136

__global__ __launch_bounds__(256, 2) void k_pside(
    const float* __restrict__ prototypes, const short* __restrict__ featbB,
    const float* __restrict__ beta_p,
    short* __restrict__ pwB, short* __restrict__ pmB, float* __restrict__ pws_neg)
{
    __shared__ char lds[35840];
    short* As = (short*)lds;
    short* Sb = (short*)lds;           // epilogue bounce (after last As use)

    const int t = threadIdx.x;
    const int w = t >> 6, lane = t & 63, l15 = lane & 15, l4 = lane >> 4;
    const int rowg = blockIdx.x >> 2, nc = blockIdx.x & 3;
    const float beta = *beta_p;

    float4v acc[4][4];
    #pragma unroll
    for (int a = 0; a < 4; ++a)
        #pragma unroll
        for (int b = 0; b < 4; ++b) acc[a][b] = (float4v){0.f, 0.f, 0.f, 0.f};

    const float* pbase = prototypes + (size_t)rowg * 128 * Dsz;

    for (int kc = 0; kc < 4; ++kc) {
        __syncthreads();
        #pragma unroll
        for (int j = 0; j < 8; ++j) {
            int idx = j * 1024 + t * 4;
            int r = idx >> 6, c = idx & 63;
            float4v v = *(const float4v*)(pbase + (size_t)r * Dsz + kc * 64 + c);
            int unit = r * 8 + ((c >> 3) ^ (r & 7));
            short4v s; s.x = f2bf(v.x); s.y = f2bf(v.y); s.z = f2bf(v.z); s.w = f2bf(v.w);
            *(short4v*)((char*)As + unit * 16 + (c & 7) * 2) = s;
        }
        __syncthreads();
        #pragma unroll
        for (int kk = 0; kk < 2; ++kk) {
            short8 af[4], bf[4];
            const int k8 = kk * 4 + l4;
            #pragma unroll
            for (int tm = 0; tm < 4; ++tm) {
                int m = (w & 1) * 64 + tm * 16 + l15;
                af[tm] = *(const short8*)&As[(m * 8 + (k8 ^ (m & 7))) * 8];
            }
            #pragma unroll
            for (int tn = 0; tn < 4; ++tn) {
                int fcb = nc * 8 + (w >> 1) * 4 + tn;
                bf[tn] = *(const short8*)&featbB[(size_t)fcb * 4096 +
                                                 (size_t)(kc * 2 + kk) * 512 + (size_t)lane * 8];
            }
            #pragma unroll
            for (int tm = 0; tm < 4; ++tm)
                #pragma unroll
                for (int tn = 0; tn < 4; ++tn)
                    acc[tm][tn] = __builtin_amdgcn_mfma_f32_16x16x32_bf16(af[tm], bf[tn], acc[tm][tn], 0, 0, 0);
        }
    }
    __syncthreads();
    #pragma unroll
    for (int tm = 0; tm < 4; ++tm)
        #pragma unroll
        for (int tn = 0; tn < 4; ++tn)
            #pragma unroll
            for (int r = 0; r < 4; ++r) {
                int row = (w & 1) * 64 + tm * 16 + l4 * 4 + r;
                int col = (w >> 1) * 64 + tn * 16 + l15;
                Sb[row * SBPITCH + col] = f2bf(acc[tm][tn][r]);
            }
    __syncthreads();
    #pragma unroll
    for (int rep = 0; rep < 8; ++rep) {
        int u = rep * 256 + t;
        int row = u >> 4, i = u & 15;
        short8 sv = *(const short8*)&Sb[row * SBPITCH + i * 8];
        short8 pwv, pmv;
        float sum = 0.f;
        #pragma unroll
        for (int e = 0; e < 8; ++e) {
            float pf = bf2f(sv[e]);
            float pp = fmaxf(pf, 0.f);
            float pw = pf * pp;
            pwv[e] = f2bf(pw);
            pmv[e] = f2bf(pp - 1.0f);
            sum += pw;
        }
        int p = rowg * 128 + row;
        int gcol = nc * 128 + i * 8;
        // fragment-ordered store
        size_t fo = (size_t)(gcol >> 4) * 4096 + (size_t)(p >> 6) * 1024 +
                    (size_t)((p >> 5) & 1) * 512 +
                    (size_t)((p & 31) + 32 * ((gcol >> 3) & 1)) * 8;
        *(short8*)&pwB[fo] = pwv;
        *(short8*)&pmB[fo] = pmv;
        #pragma unroll
        for (int mk = 1; mk < 16; mk <<= 1) sum += __shfl_xor(sum, mk, 64);
        if ((lane & 15) == 0) atomicAdd(&pws_neg[p], -beta * sum);
    }
}

// ---------------- k_main: fused, zero staging, dbuf A12, 1 barrier/chunk ----------------
__global__ __launch_bounds__(256, 3) void k_main(
    const float* __restrict__ x, const short* __restrict__ featbB,
    const short* __restrict__ pwB, const short* __restrict__ pmB,
    const float* __restrict__ pws_neg,
    const float* __restrict__ alpha_p, const float* __restrict__ beta_p,
    const float* __restrict__ theta_p, float* __restrict__ out)
{
    __shared__ short A12[4096];   // 2 bufs x [64 m][4 units][8], 8 KB total

    const int t = threadIdx.x;
    const int w = t >> 6, lane = t & 63, l15 = lane & 15, l4 = lane >> 4;
    const int l31 = lane & 31, half = lane >> 5;
    const float alpha = *alpha_p, beta = *beta_p, theta = *theta_p;
    const size_t row0 = (size_t)blockIdx.x * 64;

    // ---- x A-frags: 16 rows per wave, direct global -> regs ----
    short8 xreg[8];
    {
        const float* xr = x + (row0 + 16 * w + l15) * Dsz + l4 * 8;
        #pragma unroll
        for (int kk = 0; kk < 8; ++kk) {
            float4v v0 = *(const float4v*)(xr + kk * 32);
            float4v v1 = *(const float4v*)(xr + kk * 32 + 4);
            short8 s;
            s[0] = f2bf(v0.x); s[1] = f2bf(v0.y); s[2] = f2bf(v0.z); s[3] = f2bf(v0.w);
            s[4] = f2bf(v1.x); s[5] = f2bf(v1.y); s[6] = f2bf(v1.z); s[7] = f2bf(v1.w);
            xreg[kk] = s;
        }
    }

    float16v acc[2][2];
    #pragma unroll
    for (int a = 0; a < 2; ++a)
        #pragma unroll
        for (int b = 0; b < 2; ++b)
            #pragma unroll
            for (int e = 0; e < 16; ++e) acc[a][b][e] = 0.f;

    const int mbase = 16 * w + l4 * 4;

    for (int fc = 0; fc < 32; ++fc) {
        const int buf = (fc & 1) << 11;            // short offset of this chunk's A12 buffer

        // ---- stage 1: two independent MFMA chains, B-frags direct from L1/L2 ----
        const short* fbase = featbB + (size_t)fc * 4096 + (size_t)lane * 8;
        float4v s0 = (float4v){0.f, 0.f, 0.f, 0.f};
        float4v s1 = (float4v){0.f, 0.f, 0.f, 0.f};
        #pragma unroll
        for (int kk = 0; kk < 8; kk += 2) {
            short8 b0 = *(const short8*)(fbase + kk * 512);
            short8 b1 = *(const short8*)(fbase + kk * 512 + 512);
            s0 = __builtin_amdgcn_mfma_f32_16x16x32_bf16(xreg[kk],     b0, s0, 0, 0, 0);
            s1 = __builtin_amdgcn_mfma_f32_16x16x32_bf16(xreg[kk + 1], b1, s1, 0, 0, 0);
        }

        // ---- epilogue: Tversky weights -> A12 dbuf (XOR-unit swizzle) ----
        #pragma unroll
        for (int r = 0; r < 4; ++r) {
            float sv = s0[r] + s1[r];
            float xp = fmaxf(sv, 0.f);
            float xw = sv * xp;
            int m = mbase + r;
            int swz = (m >> 2) & 3;
            int u1 = m * 4 + ((l15 >> 3) ^ swz);
            int u2 = m * 4 + ((2 | (l15 >> 3)) ^ swz);
            A12[buf + u1 * 8 + (l15 & 7)] = f2bf(theta * xw + beta * xp);
            A12[buf + u2 * 8 + (l15 & 7)] = f2bf(alpha * xw);
        }

        // ---- stage-2 B-frags (independent of barrier; issue early) ----
        const short* pb = pwB + (size_t)fc * 4096 + (size_t)w * 1024 + (size_t)lane * 8;
        const short* mb = pmB + (size_t)fc * 4096 + (size_t)w * 1024 + (size_t)lane * 8;
        short8 bw0 = *(const short8*)(pb);
        short8 bw1 = *(const short8*)(pb + 512);
        short8 bm0 = *(const short8*)(mb);
        short8 bm1 = *(const short8*)(mb + 512);

        __syncthreads();                           // A12[buf] written by all; prev-buf reads done

        // ---- stage 2: A-frags from A12, 8 MFMA 32x32x16 ----
        short8 a1f[2], a2f[2];
        #pragma unroll
        for (int mi = 0; mi < 2; ++mi) {
            int m = 32 * mi + l31;
            int swz = (m >> 2) & 3;
            a1f[mi] = *(const short8*)&A12[buf + (m * 4 + (half ^ swz)) * 8];
            a2f[mi] = *(const short8*)&A12[buf + (m * 4 + ((2 | half) ^ swz)) * 8];
        }
        #pragma unroll
        for (int mi = 0; mi < 2; ++mi) {
            acc[mi][0] = __builtin_amdgcn_mfma_f32_32x32x16_bf16(a1f[mi], bw0, acc[mi][0], 0, 0, 0);
            acc[mi][0] = __builtin_amdgcn_mfma_f32_32x32x16_bf16(a2f[mi], bm0, acc[mi][0], 0, 0, 0);
            acc[mi][1] = __builtin_amdgcn_mfma_f32_32x32x16_bf16(a1f[mi], bw1, acc[mi][1], 0, 0, 0);
            acc[mi][1] = __builtin_amdgcn_mfma_f32_32x32x16_bf16(a2f[mi], bm1, acc[mi][1], 0, 0, 0);
        }
    }

    // ---- output: 32x32 C layout col=lane&31, row=(reg&3)+8*(reg>>2)+4*(lane>>5) ----
    #pragma unroll
    for (int ni = 0; ni < 2; ++ni) {
        int col = 64 * w + 32 * ni + l31;
        float pn = pws_neg[col];
        #pragma unroll
        for (int mi = 0; mi < 2; ++mi)
            #pragma unroll
            for (int rg = 0; rg < 16; ++rg) {
                size_t grow = row0 + 32 * mi + (rg & 3) + 8 * (rg >> 2) + 4 * half;
                out[grow * Psz + col] = acc[mi][ni][rg] + pn;
            }
    }
}

// ---------------- launcher ----------------
extern "C" void kernel_launch(void* const* d_in, const int* in_sizes, int n_in,
                              void* d_out, int out_size, void* d_ws, size_t ws_size,
                              hipStream_t stream) {
    const float* x          = (const float*)d_in[0];
    const float* features   = (const float*)d_in[1];
    const float* prototypes = (const float*)d_in[2];
    const float* alpha      = (const float*)d_in[3];
    const float* beta       = (const float*)d_in[4];
    const float* theta      = (const float*)d_in[5];
    float* out = (float*)d_out;

    // ws: featbB 256KB @0, pwB 256KB @262144, pmB 256KB @524288, pws_neg 1KB @786432
    char* ws = (char*)d_ws;
    short* featbB  = (short*)(ws);
    short* pwB     = (short*)(ws + 262144);
    short* pmB     = (short*)(ws + 524288);
    float* pws_neg = (float*)(ws + 786432);

    hipLaunchKernelGGL(k_prep,  dim3(64),   dim3(256), 0, stream, features, featbB, pws_neg);
    hipLaunchKernelGGL(k_pside, dim3(8),    dim3(256), 0, stream, prototypes, featbB, beta,
                       pwB, pmB, pws_neg);
    hipLaunchKernelGGL(k_main,  dim3(1024), dim3(256), 0, stream, x, featbB, pwB, pmB,
                       pws_neg, alpha, beta, theta, out);
}